// Round 3
// baseline (495.991 us; speedup 1.0000x reference)
//
#include <hip/hip_runtime.h>
#include <stdint.h>

#define NB_CHUNKS 1024
#define BROWS 128

// ---------------- Kernel A: per-row stats ----------------
__global__ __launch_bounds__(256) void rowstats(
    const float* __restrict__ x, const float* __restrict__ w,
    const float* __restrict__ bias, const float* __restrict__ w1p,
    const float* __restrict__ bp,
    float* __restrict__ support, float* __restrict__ coef,
    double* __restrict__ base, int N)
{
    int wv = threadIdx.x >> 6, lane = threadIdx.x & 63;
    int row = blockIdx.x * 4 + wv;
    if (row >= N) return;
    const float4* xr = (const float4*)(x + (size_t)row * 512);
    const float4* wr = (const float4*)(w);
    float dot = 0.f, ss = 0.f;
#pragma unroll
    for (int it = 0; it < 2; it++) {
        float4 xv = xr[lane + it * 64];
        float4 wv4 = wr[lane + it * 64];
        dot += xv.x * wv4.x + xv.y * wv4.y + xv.z * wv4.z + xv.w * wv4.w;
        ss  += xv.x * xv.x + xv.y * xv.y + xv.z * xv.z + xv.w * xv.w;
    }
    for (int off = 32; off; off >>= 1) {
        dot += __shfl_xor(dot, off);
        ss  += __shfl_xor(ss, off);
    }
    if (lane == 0) {
        double n = sqrt((double)ss); if (n < 1e-15) n = 1e-15;
        double t = n; const double lim = 1.0 - 1e-7; if (t > lim) t = lim;
        double cf = atanh(t) / n;
        double s = cf * (double)dot;
        double b0 = (double)bias[0];
        double nb = fabs(b0); if (nb < 1e-15) nb = 1e-15;
        double hb = tanh(nb) * b0 / nb;
        const double maxn = 0.996;
        double nh = fabs(hb); if (nh < 1e-15) nh = 1e-15;
        if (nh > maxn) hb = hb / nh * maxn;
        double x2 = s * s, y2 = hb * hb, xy = s * hb;
        double num = (1.0 + 2.0 * xy + y2) * s + (1.0 - x2) * hb;
        double den = 1.0 + 2.0 * xy + x2 * y2;
        if (den < 1e-15) den = 1e-15;
        double r = num / den;
        double nr = fabs(r); if (nr < 1e-15) nr = 1e-15;
        if (nr > maxn) r = r / nr * maxn;
        support[row] = (float)r;
        coef[row] = (float)cf;
        double w1 = (double)w1p[0];
        double bb = (double)bp[0];
        base[row] = (1.0 - w1) * (1.0 - n) + bb;
    }
}

// ---------------- fallback SpMV (atomic, used only if ws too small) -------
__global__ __launch_bounds__(256) void spmv(
    const int* __restrict__ rows, const int* __restrict__ cols,
    const float* __restrict__ adj, const float* __restrict__ support,
    unsigned long long* __restrict__ agg, int E)
{
    int e = blockIdx.x * 256 + threadIdx.x;
    if (e >= E) return;
    double p = (double)adj[e] * (double)support[cols[e]];
    long long f = llrint(p * 1073741824.0); // 2^30
    atomicAdd(&agg[rows[e]], (unsigned long long)f);
}

// ---------------- binned SpMV phase 1: per-chunk histogram ----------------
__global__ __launch_bounds__(256) void edge_hist(
    const int* __restrict__ rows, uint32_t* __restrict__ P,
    int E, int chunk, int nbuk)
{
    __shared__ uint32_t h[1024];
    int b = blockIdx.x;
    for (int q = threadIdx.x; q < nbuk; q += 256) h[q] = 0u;
    __syncthreads();
    int s = b * chunk, e_end = min(E, s + chunk);
    for (int i = s + threadIdx.x; i < e_end; i += 256)
        atomicAdd(&h[((uint32_t)rows[i]) >> 7], 1u);
    __syncthreads();
    for (int q = threadIdx.x; q < nbuk; q += 256)
        P[(size_t)q * NB_CHUNKS + b] = h[q];
}

// phase 2a: per-bucket exclusive scan over chunks (one wave per bucket)
__global__ __launch_bounds__(64) void scan_parts(
    uint32_t* __restrict__ P, uint32_t* __restrict__ tot)
{
    int q = blockIdx.x, lane = threadIdx.x;
    uint32_t* row = P + (size_t)q * NB_CHUNKS;
    uint32_t v[16]; uint32_t s = 0;
#pragma unroll
    for (int j = 0; j < 16; j++) { v[j] = row[lane * 16 + j]; s += v[j]; }
    uint32_t inc = s;
    for (int off = 1; off < 64; off <<= 1) {
        uint32_t t = __shfl_up(inc, off);
        if (lane >= off) inc += t;
    }
    uint32_t run = inc - s;
#pragma unroll
    for (int j = 0; j < 16; j++) { uint32_t c = v[j]; row[lane * 16 + j] = run; run += c; }
    if (lane == 63) tot[q] = inc;
}

// phase 2b: exclusive scan of bucket totals -> base[nbuk+1]
__global__ __launch_bounds__(1024) void scan_base(
    const uint32_t* __restrict__ tot, uint32_t* __restrict__ bas, int nbuk)
{
    __shared__ uint32_t lds[1024];
    int t = threadIdx.x;
    uint32_t v = (t < nbuk) ? tot[t] : 0u;
    lds[t] = v;
    __syncthreads();
    for (int off = 1; off < 1024; off <<= 1) {
        uint32_t u = (t >= off) ? lds[t - off] : 0u;
        __syncthreads();
        lds[t] += u;
        __syncthreads();
    }
    if (t == 0) bas[0] = 0u;
    if (t < nbuk) bas[t + 1] = lds[t];
}

// phase 3: scatter fixed-point products into bucket segments
__global__ __launch_bounds__(256) void edge_scatter(
    const int* __restrict__ rows, const int* __restrict__ cols,
    const float* __restrict__ adj, const float* __restrict__ support,
    const uint32_t* __restrict__ P, const uint32_t* __restrict__ bas,
    int* __restrict__ prod, uint8_t* __restrict__ rowlo,
    int E, int chunk, int nbuk)
{
    __shared__ uint32_t cur[1024];
    int b = blockIdx.x;
    for (int q = threadIdx.x; q < nbuk; q += 256)
        cur[q] = bas[q] + P[(size_t)q * NB_CHUNKS + b];
    __syncthreads();
    int s = b * chunk, e_end = min(E, s + chunk);
    for (int i = s + threadIdx.x; i < e_end; i += 256) {
        uint32_t r = (uint32_t)rows[i];
        double p = (double)adj[i] * (double)support[cols[i]];
        int pi = (int)llrint(p * 1073741824.0); // 2^30
        uint32_t pos = atomicAdd(&cur[r >> 7], 1u);
        prod[pos] = pi;
        rowlo[pos] = (uint8_t)(r & 127u);
    }
}

// phase 4: per-bucket LDS reduction -> agg
__global__ __launch_bounds__(256) void bucket_reduce(
    const int* __restrict__ prod, const uint8_t* __restrict__ rowlo,
    const uint32_t* __restrict__ bas, unsigned long long* __restrict__ agg, int N)
{
    __shared__ unsigned long long acc[BROWS];
    int q = blockIdx.x;
    for (int r = threadIdx.x; r < BROWS; r += 256) acc[r] = 0ull;
    __syncthreads();
    uint32_t s = bas[q], e = bas[q + 1];
    for (uint32_t i = s + threadIdx.x; i < e; i += 256)
        atomicAdd(&acc[rowlo[i]], (unsigned long long)(long long)prod[i]);
    __syncthreads();
    int rbase = q * BROWS;
    for (int r = threadIdx.x; r < BROWS; r += 256) {
        int gr = rbase + r;
        if (gr < N) agg[gr] = acc[r];
    }
}

// ---------------- Kernel C: attn + keys + coarse histogram ----------------
__global__ __launch_bounds__(256) void attn_kernel(
    const unsigned long long* __restrict__ agg, const double* __restrict__ base,
    const float* __restrict__ w1p,
    float* __restrict__ attn, uint32_t* __restrict__ keys,
    uint32_t* __restrict__ hist1, float* __restrict__ attn_out, int N)
{
    int i = blockIdx.x * 256 + threadIdx.x;
    if (i >= N) return;
    double a = (double)(long long)agg[i] * (1.0 / 1073741824.0);
    double na = fabs(a); if (na < 1e-15) na = 1e-15;
    double sc_ = tanh(na) * a / na;
    const double maxn = 0.996;
    double ns = fabs(sc_); if (ns < 1e-15) ns = 1e-15;
    if (ns > maxn) sc_ = sc_ / ns * maxn;
    double w1 = (double)w1p[0];
    double at = w1 * tanh(sc_) + base[i];
    float af = (float)at;
    attn[i] = af;
    attn_out[i] = af;
    union { float f; uint32_t u; } cv; cv.f = af;
    uint32_t key = cv.u ^ ((cv.u >> 31) ? 0xFFFFFFFFu : 0x80000000u);
    keys[i] = key;
    atomicAdd(&hist1[key >> 16], 1u);
}

// ---------------- find bucket containing k-th largest ----------------
__global__ __launch_bounds__(1024) void select_bucket(
    const uint32_t* __restrict__ hist, uint32_t* M, int mode, uint32_t k)
{
    __shared__ uint32_t lds[1024];
    int t = threadIdx.x;
    uint32_t ktarget = (mode == 0) ? k : (k - M[1]);
    uint32_t csum = 0;
    for (int j = 0; j < 64; j++) csum += hist[t * 64 + j];
    lds[t] = csum;
    __syncthreads();
    for (int off = 1; off < 1024; off <<= 1) {
        uint32_t v = (t + off < 1024) ? lds[t + off] : 0u;
        __syncthreads();
        lds[t] += v;
        __syncthreads();
    }
    uint32_t run = (t + 1 < 1024) ? lds[t + 1] : 0u;
    for (int j = 63; j >= 0; j--) {
        uint32_t c = hist[t * 64 + j];
        uint32_t nr = run + c;
        if (nr >= ktarget && run < ktarget) {
            if (mode == 0) { M[0] = (uint32_t)(t * 64 + j); M[1] = run; }
            else           { M[2] = (M[0] << 16) | (uint32_t)(t * 64 + j); }
        }
        run = nr;
    }
}

__global__ __launch_bounds__(256) void hist_low(
    const uint32_t* __restrict__ keys, const uint32_t* __restrict__ M,
    uint32_t* __restrict__ hist2, int N)
{
    int i = blockIdx.x * 256 + threadIdx.x;
    if (i >= N) return;
    uint32_t key = keys[i];
    if ((key >> 16) == M[0]) atomicAdd(&hist2[key & 0xFFFFu], 1u);
}

// ---------------- selection prefix machinery ----------------
__global__ __launch_bounds__(256) void blocksum(
    const uint32_t* __restrict__ keys, const uint32_t* __restrict__ M,
    uint32_t* __restrict__ bs, uint32_t* __restrict__ bt, int N)
{
    __shared__ uint32_t ls[4], lt[4];
    uint32_t tau = M[2];
    int base_i = blockIdx.x * 1024 + threadIdx.x * 4;
    uint32_t cs = 0, ct = 0;
    for (int j = 0; j < 4; j++) {
        int i = base_i + j;
        if (i < N) {
            uint32_t kk = keys[i];
            cs += (kk > tau);
            ct += (kk == tau);
        }
    }
    for (int off = 32; off; off >>= 1) {
        cs += __shfl_xor(cs, off);
        ct += __shfl_xor(ct, off);
    }
    int lane = threadIdx.x & 63, wv = threadIdx.x >> 6;
    if (lane == 0) { ls[wv] = cs; lt[wv] = ct; }
    __syncthreads();
    if (threadIdx.x == 0) {
        uint32_t a = 0, b = 0;
        for (int wq = 0; wq < 4; wq++) { a += ls[wq]; b += lt[wq]; }
        bs[blockIdx.x] = a; bt[blockIdx.x] = b;
    }
}

__global__ __launch_bounds__(128) void scanblocks(
    uint32_t* M, const uint32_t* __restrict__ bsv, const uint32_t* __restrict__ btv,
    uint32_t* __restrict__ ssv, uint32_t* __restrict__ stv, int nb, uint32_t k)
{
    __shared__ uint32_t A[128], B[128];
    int t = threadIdx.x;
    if (nb <= 128) {
        uint32_t a = (t < nb) ? bsv[t] : 0u;
        uint32_t b = (t < nb) ? btv[t] : 0u;
        A[t] = a; B[t] = b;
        __syncthreads();
        for (int off = 1; off < 128; off <<= 1) {
            uint32_t ua = (t >= off) ? A[t - off] : 0u;
            uint32_t ub = (t >= off) ? B[t - off] : 0u;
            __syncthreads();
            A[t] += ua; B[t] += ub;
            __syncthreads();
        }
        if (t < nb) { ssv[t] = A[t] - a; stv[t] = B[t] - b; }
        if (t == 127) M[3] = k - A[127];
    } else if (t == 0) {
        uint32_t a = 0, b = 0;
        for (int i = 0; i < nb; i++) {
            ssv[i] = a; stv[i] = b;
            a += bsv[i]; b += btv[i];
        }
        M[3] = k - a;
    }
}

__global__ __launch_bounds__(256) void select_write(
    const uint32_t* __restrict__ keys, const uint32_t* __restrict__ M,
    const uint32_t* __restrict__ ss, const uint32_t* __restrict__ st,
    uint32_t* __restrict__ sel, int N)
{
    uint32_t tau = M[2], need = M[3];
    int t = threadIdx.x, lane = t & 63, wv = t >> 6;
    int base_i = blockIdx.x * 1024 + t * 4;
    uint32_t fs[4], ft[4];
    uint32_t cs = 0, ct = 0;
    for (int j = 0; j < 4; j++) {
        int i = base_i + j;
        uint32_t kk = (i < N) ? keys[i] : 0u;
        fs[j] = (i < N) && (kk > tau);
        ft[j] = (i < N) && (kk == tau);
        cs += fs[j]; ct += ft[j];
    }
    uint32_t is_ = cs, it_ = ct;
    for (int off = 1; off < 64; off <<= 1) {
        uint32_t vs = __shfl_up(is_, off);
        uint32_t vt = __shfl_up(it_, off);
        if (lane >= off) { is_ += vs; it_ += vt; }
    }
    uint32_t wes = is_ - cs, wet = it_ - ct;
    __shared__ uint32_t lws[4], lwt[4];
    if (lane == 63) { lws[wv] = is_; lwt[wv] = it_; }
    __syncthreads();
    uint32_t wos = 0, wot = 0;
    for (int wq = 0; wq < wv; wq++) { wos += lws[wq]; wot += lwt[wq]; }
    uint32_t gs = ss[blockIdx.x] + wos + wes;
    uint32_t gt = st[blockIdx.x] + wot + wet;
    for (int j = 0; j < 4; j++) {
        int i = base_i + j;
        if (fs[j]) {
            uint32_t pos = gs + (gt < need ? gt : need);
            sel[pos] = (uint32_t)i;
        } else if (ft[j]) {
            if (gt < need) sel[gs + gt] = (uint32_t)i;
        }
        gs += fs[j]; gt += ft[j];
    }
}

// ---------------- Kernel E: write hidden rows ----------------
__global__ __launch_bounds__(256) void write_hidden(
    const float* __restrict__ x, const uint32_t* __restrict__ sel,
    const float* __restrict__ attn, const float* __restrict__ coef,
    float* __restrict__ out, int K)
{
    int wv = threadIdx.x >> 6, lane = threadIdx.x & 63;
    int p = blockIdx.x * 4 + wv;
    if (p >= K) return;
    uint32_t i = sel[p];
    float s = attn[i] * coef[i];
    const float4* xr = (const float4*)(x + (size_t)i * 512);
    float4* orow = (float4*)(out + (size_t)p * 512);
#pragma unroll
    for (int it = 0; it < 2; it++) {
        float4 v = xr[lane + it * 64];
        float4 o;
        o.x = v.x * s; o.y = v.y * s; o.z = v.z * s; o.w = v.w * s;
        orow[lane + it * 64] = o;
    }
}

extern "C" void kernel_launch(void* const* d_in, const int* in_sizes, int n_in,
                              void* d_out, int out_size, void* d_ws, size_t ws_size,
                              hipStream_t stream)
{
    const float* x    = (const float*)d_in[0];
    const float* adj  = (const float*)d_in[1];
    const float* w    = (const float*)d_in[2];
    const float* bias = (const float*)d_in[3];
    const float* w1p  = (const float*)d_in[4];
    const float* bp   = (const float*)d_in[5];
    const int* erow = (const int*)d_in[6];
    const int* ecol = (const int*)d_in[7];

    int D = in_sizes[2];          // 512
    int N = in_sizes[0] / D;      // 100000
    int E = in_sizes[1];          // 3200000
    int K = N / 2;                // keep_ratio 0.5

    char* ws = (char*)d_ws;
    float*   support = (float*)(ws);                                  // N*4 @ 0
    float*   coef    = (float*)(ws + (512 << 10));                    // N*4 @ 0.5M
    double*  base    = (double*)(ws + (1 << 20));                     // N*8 @ 1M
    float*   attn    = (float*)(ws + (2 << 20));                      // N*4 @ 2M
    uint32_t* keys   = (uint32_t*)(ws + (2 << 20) + (512 << 10));     // N*4 @ 2.5M
    unsigned long long* agg = (unsigned long long*)(ws + (3 << 20));  // N*8 @ 3M
    uint32_t* hist1  = (uint32_t*)(ws + (4 << 20));                   // 256K @ 4M
    uint32_t* hist2  = (uint32_t*)(ws + (4 << 20) + (256 << 10));     // 256K @ 4.25M
    uint32_t* M      = (uint32_t*)(ws + 4718592);                     // @ 4.5M
    uint32_t* bsv = M + 8;
    uint32_t* btv = M + 8 + 128;
    uint32_t* ssv = M + 8 + 256;
    uint32_t* stv = M + 8 + 384;
    uint32_t* sel  = (uint32_t*)(ws + 4849664);                       // K*4 @ 4.625M
    uint32_t* tot  = (uint32_t*)(ws + 5242880);                       // @ 5M
    uint32_t* bas  = (uint32_t*)(ws + 5242880 + 4096);                // @ 5M+4K
    uint32_t* P    = (uint32_t*)(ws + 5242880 + 16384);               // nbuk*1024*4 @ 5M+16K (<= 3.3M)
    int*      prod = (int*)(ws + (9 << 20));                          // E*4 @ 9M (12.8M)
    uint8_t*  rowlo= (uint8_t*)(ws + (22 << 20));                     // E @ 22M (3.2M)

    float* hidden_out = (float*)d_out;
    float* attn_out   = (float*)d_out + (size_t)K * D;

    int nbuk = (N + BROWS - 1) / BROWS;        // 782
    int chunk = (E + NB_CHUNKS - 1) / NB_CHUNKS;
    bool fast = (ws_size >= (size_t)(26 << 20)) && (nbuk <= 1024);

    hipMemsetAsync(ws + (4 << 20), 0, (512 << 10) + 4096, stream); // hist1,hist2,M

    rowstats<<<(N + 3) / 4, 256, 0, stream>>>(x, w, bias, w1p, bp, support, coef, base, N);

    if (fast) {
        edge_hist<<<NB_CHUNKS, 256, 0, stream>>>(erow, P, E, chunk, nbuk);
        scan_parts<<<nbuk, 64, 0, stream>>>(P, tot);
        scan_base<<<1, 1024, 0, stream>>>(tot, bas, nbuk);
        edge_scatter<<<NB_CHUNKS, 256, 0, stream>>>(erow, ecol, adj, support, P, bas,
                                                    prod, rowlo, E, chunk, nbuk);
        bucket_reduce<<<nbuk, 256, 0, stream>>>(prod, rowlo, bas, agg, N);
    } else {
        hipMemsetAsync(agg, 0, (size_t)N * 8, stream);
        spmv<<<(E + 255) / 256, 256, 0, stream>>>(erow, ecol, adj, support, agg, E);
    }

    attn_kernel<<<(N + 255) / 256, 256, 0, stream>>>(agg, base, w1p, attn, keys, hist1, attn_out, N);
    select_bucket<<<1, 1024, 0, stream>>>(hist1, M, 0, (uint32_t)K);
    hist_low<<<(N + 255) / 256, 256, 0, stream>>>(keys, M, hist2, N);
    select_bucket<<<1, 1024, 0, stream>>>(hist2, M, 1, (uint32_t)K);
    int nb = (N + 1023) / 1024;
    blocksum<<<nb, 256, 0, stream>>>(keys, M, bsv, btv, N);
    scanblocks<<<1, 128, 0, stream>>>(M, bsv, btv, ssv, stv, nb, (uint32_t)K);
    select_write<<<nb, 256, 0, stream>>>(keys, M, ssv, stv, sel, N);
    write_hidden<<<(K + 3) / 4, 256, 0, stream>>>(x, sel, attn, coef, hidden_out, K);
}

// Round 4
// 409.849 us; speedup vs baseline: 1.2102x; 1.2102x over previous
//
#include <hip/hip_runtime.h>
#include <stdint.h>

#define CHUNK 3072
#define BROWS 256   // rows per bucket (q = row >> 8)

// ---------------- Kernel A: per-row stats ----------------
__global__ __launch_bounds__(256) void rowstats(
    const float* __restrict__ x, const float* __restrict__ w,
    const float* __restrict__ bias, const float* __restrict__ w1p,
    const float* __restrict__ bp,
    float* __restrict__ support, float* __restrict__ coef,
    double* __restrict__ base, int N)
{
    int wv = threadIdx.x >> 6, lane = threadIdx.x & 63;
    int row = blockIdx.x * 4 + wv;
    if (row >= N) return;
    const float4* xr = (const float4*)(x + (size_t)row * 512);
    const float4* wr = (const float4*)(w);
    float dot = 0.f, ss = 0.f;
#pragma unroll
    for (int it = 0; it < 2; it++) {
        float4 xv = xr[lane + it * 64];
        float4 wv4 = wr[lane + it * 64];
        dot += xv.x * wv4.x + xv.y * wv4.y + xv.z * wv4.z + xv.w * wv4.w;
        ss  += xv.x * xv.x + xv.y * xv.y + xv.z * xv.z + xv.w * xv.w;
    }
    for (int off = 32; off; off >>= 1) {
        dot += __shfl_xor(dot, off);
        ss  += __shfl_xor(ss, off);
    }
    if (lane == 0) {
        double n = sqrt((double)ss); if (n < 1e-15) n = 1e-15;
        double t = n; const double lim = 1.0 - 1e-7; if (t > lim) t = lim;
        double cf = atanh(t) / n;
        double s = cf * (double)dot;
        double b0 = (double)bias[0];
        double nb = fabs(b0); if (nb < 1e-15) nb = 1e-15;
        double hb = tanh(nb) * b0 / nb;
        const double maxn = 0.996;
        double nh = fabs(hb); if (nh < 1e-15) nh = 1e-15;
        if (nh > maxn) hb = hb / nh * maxn;
        double x2 = s * s, y2 = hb * hb, xy = s * hb;
        double num = (1.0 + 2.0 * xy + y2) * s + (1.0 - x2) * hb;
        double den = 1.0 + 2.0 * xy + x2 * y2;
        if (den < 1e-15) den = 1e-15;
        double r = num / den;
        double nr = fabs(r); if (nr < 1e-15) nr = 1e-15;
        if (nr > maxn) r = r / nr * maxn;
        support[row] = (float)r;
        coef[row] = (float)cf;
        double w1 = (double)w1p[0];
        double bb = (double)bp[0];
        base[row] = (1.0 - w1) * (1.0 - n) + bb;
    }
}

// ---------------- fallback SpMV (atomic) ----------------
__global__ __launch_bounds__(256) void spmv(
    const int* __restrict__ rows, const int* __restrict__ cols,
    const float* __restrict__ adj, const float* __restrict__ support,
    unsigned long long* __restrict__ agg, int E)
{
    int e = blockIdx.x * 256 + threadIdx.x;
    if (e >= E) return;
    double p = (double)adj[e] * (double)support[cols[e]];
    long long f = llrint(p * 1073741824.0); // 2^30
    atomicAdd(&agg[rows[e]], (unsigned long long)f);
}

// ---------------- phase 1: per-chunk histogram ----------------
__global__ __launch_bounds__(256) void edge_hist(
    const int* __restrict__ rows, uint32_t* __restrict__ P,
    int E, int nbuk, int nchunks)
{
    __shared__ uint32_t h[512];
    int b = blockIdx.x;
    for (int q = threadIdx.x; q < 512; q += 256) h[q] = 0u;
    __syncthreads();
    int s = b * CHUNK, e_end = min(E, s + CHUNK);
    for (int i = s + threadIdx.x; i < e_end; i += 256)
        atomicAdd(&h[((uint32_t)rows[i]) >> 8], 1u);
    __syncthreads();
    for (int q = threadIdx.x; q < nbuk; q += 256)
        P[(size_t)q * nchunks + b] = h[q];
}

// phase 2a: per-bucket exclusive scan over chunks (one wave per bucket)
__global__ __launch_bounds__(64) void scan_parts(
    uint32_t* __restrict__ P, uint32_t* __restrict__ tot, int nchunks)
{
    int q = blockIdx.x, lane = threadIdx.x;
    uint32_t* row = P + (size_t)q * nchunks;
    uint32_t run = 0;
    for (int base = 0; base < nchunks; base += 64) {
        int idx = base + lane;
        uint32_t v = (idx < nchunks) ? row[idx] : 0u;
        uint32_t inc = v;
        for (int off = 1; off < 64; off <<= 1) {
            uint32_t t = __shfl_up(inc, off);
            if (lane >= off) inc += t;
        }
        if (idx < nchunks) row[idx] = run + inc - v;
        run += __shfl(inc, 63);
    }
    if (lane == 0) tot[q] = run;
}

// phase 2b: exclusive scan of bucket totals -> bas[nbuk+1]
__global__ __launch_bounds__(1024) void scan_base(
    const uint32_t* __restrict__ tot, uint32_t* __restrict__ bas, int nbuk)
{
    __shared__ uint32_t lds[1024];
    int t = threadIdx.x;
    uint32_t v = (t < nbuk) ? tot[t] : 0u;
    lds[t] = v;
    __syncthreads();
    for (int off = 1; off < 1024; off <<= 1) {
        uint32_t u = (t >= off) ? lds[t - off] : 0u;
        __syncthreads();
        lds[t] += u;
        __syncthreads();
    }
    if (t == 0) bas[0] = 0u;
    if (t < nbuk) bas[t + 1] = lds[t];
}

// phase 3: block-local counting sort in LDS, then coalesced dump
__global__ __launch_bounds__(256) void edge_sort_scatter(
    const int* __restrict__ rows, const int* __restrict__ cols,
    const float* __restrict__ adj, const float* __restrict__ support,
    const uint32_t* __restrict__ P, const uint32_t* __restrict__ bas,
    int* __restrict__ prod, uint8_t* __restrict__ rowlo,
    int E, int nbuk, int nchunks)
{
    __shared__ uint32_t lcnt[512], lofs[512], gbase[512], sc[512];
    __shared__ int      lpi[CHUNK];
    __shared__ uint16_t lq[CHUNK];
    __shared__ uint8_t  lrl[CHUNK];
    int b = blockIdx.x, t = threadIdx.x;
    int s = b * CHUNK;
    int n = min(CHUNK, E - s);
    if (n <= 0) return;
    for (int q = t; q < 512; q += 256) lcnt[q] = 0u;
    __syncthreads();
    for (int i = t; i < n; i += 256)
        atomicAdd(&lcnt[((uint32_t)rows[s + i]) >> 8], 1u);
    __syncthreads();
    // inclusive scan of lcnt[0..512) -> sc; lofs = exclusive
    uint32_t a0 = lcnt[t], a1 = lcnt[t + 256];
    sc[t] = a0; sc[t + 256] = a1;
    __syncthreads();
    for (int off = 1; off < 512; off <<= 1) {
        uint32_t u0 = (t >= off) ? sc[t - off] : 0u;
        uint32_t u1 = ((t + 256) >= off) ? sc[t + 256 - off] : 0u;
        __syncthreads();
        sc[t] += u0; sc[t + 256] += u1;
        __syncthreads();
    }
    lofs[t] = sc[t] - a0;
    lofs[t + 256] = sc[t + 256] - a1;
    for (int q = t; q < 512; q += 256) {
        gbase[q] = (q < nbuk) ? (bas[q] + P[(size_t)q * nchunks + b]) : 0u;
        lcnt[q] = 0u;
    }
    __syncthreads();
    // place records grouped by bucket inside LDS
    for (int i = t; i < n; i += 256) {
        uint32_t r = (uint32_t)rows[s + i];
        uint32_t q = r >> 8;
        double p = (double)adj[s + i] * (double)support[cols[s + i]];
        int pi = (int)llrint(p * 1073741824.0); // 2^30
        uint32_t rank = atomicAdd(&lcnt[q], 1u);
        uint32_t slot = lofs[q] + rank;
        lpi[slot] = pi;
        lq[slot]  = (uint16_t)q;
        lrl[slot] = (uint8_t)(r & 255u);
    }
    __syncthreads();
    // linear dump: consecutive threads -> consecutive positions per bucket run
    for (int i = t; i < n; i += 256) {
        uint32_t q = lq[i];
        uint32_t gpos = gbase[q] + ((uint32_t)i - lofs[q]);
        prod[gpos]  = lpi[i];
        rowlo[gpos] = lrl[i];
    }
}

// phase 4: per-bucket deterministic integer reduction -> agg
__global__ __launch_bounds__(256) void bucket_reduce(
    const int* __restrict__ prod, const uint8_t* __restrict__ rowlo,
    const uint32_t* __restrict__ bas, unsigned long long* __restrict__ agg, int N)
{
    __shared__ unsigned long long acc[BROWS];
    int q = blockIdx.x;
    acc[threadIdx.x] = 0ull;
    __syncthreads();
    uint32_t s = bas[q], e = bas[q + 1];
    for (uint32_t i = s + threadIdx.x; i < e; i += 256)
        atomicAdd(&acc[rowlo[i]], (unsigned long long)(long long)prod[i]);
    __syncthreads();
    int gr = q * BROWS + threadIdx.x;
    if (gr < N) agg[gr] = acc[threadIdx.x];
}

// ---------------- Kernel C: attn + keys + coarse histogram ----------------
__global__ __launch_bounds__(256) void attn_kernel(
    const unsigned long long* __restrict__ agg, const double* __restrict__ base,
    const float* __restrict__ w1p,
    float* __restrict__ attn, uint32_t* __restrict__ keys,
    uint32_t* __restrict__ hist1, float* __restrict__ attn_out, int N)
{
    int i = blockIdx.x * 256 + threadIdx.x;
    if (i >= N) return;
    double a = (double)(long long)agg[i] * (1.0 / 1073741824.0);
    double na = fabs(a); if (na < 1e-15) na = 1e-15;
    double sc_ = tanh(na) * a / na;
    const double maxn = 0.996;
    double ns = fabs(sc_); if (ns < 1e-15) ns = 1e-15;
    if (ns > maxn) sc_ = sc_ / ns * maxn;
    double w1 = (double)w1p[0];
    double at = w1 * tanh(sc_) + base[i];
    float af = (float)at;
    attn[i] = af;
    attn_out[i] = af;
    union { float f; uint32_t u; } cv; cv.f = af;
    uint32_t key = cv.u ^ ((cv.u >> 31) ? 0xFFFFFFFFu : 0x80000000u);
    keys[i] = key;
    atomicAdd(&hist1[key >> 16], 1u);
}

// ---------------- find bucket containing k-th largest ----------------
__global__ __launch_bounds__(1024) void select_bucket(
    const uint32_t* __restrict__ hist, uint32_t* M, int mode, uint32_t k)
{
    __shared__ uint32_t lds[1024];
    int t = threadIdx.x;
    uint32_t ktarget = (mode == 0) ? k : (k - M[1]);
    uint32_t csum = 0;
    for (int j = 0; j < 64; j++) csum += hist[t * 64 + j];
    lds[t] = csum;
    __syncthreads();
    for (int off = 1; off < 1024; off <<= 1) {
        uint32_t v = (t + off < 1024) ? lds[t + off] : 0u;
        __syncthreads();
        lds[t] += v;
        __syncthreads();
    }
    uint32_t run = (t + 1 < 1024) ? lds[t + 1] : 0u;
    for (int j = 63; j >= 0; j--) {
        uint32_t c = hist[t * 64 + j];
        uint32_t nr = run + c;
        if (nr >= ktarget && run < ktarget) {
            if (mode == 0) { M[0] = (uint32_t)(t * 64 + j); M[1] = run; }
            else           { M[2] = (M[0] << 16) | (uint32_t)(t * 64 + j); }
        }
        run = nr;
    }
}

__global__ __launch_bounds__(256) void hist_low(
    const uint32_t* __restrict__ keys, const uint32_t* __restrict__ M,
    uint32_t* __restrict__ hist2, int N)
{
    int i = blockIdx.x * 256 + threadIdx.x;
    if (i >= N) return;
    uint32_t key = keys[i];
    if ((key >> 16) == M[0]) atomicAdd(&hist2[key & 0xFFFFu], 1u);
}

// ---------------- selection prefix machinery ----------------
__global__ __launch_bounds__(256) void blocksum(
    const uint32_t* __restrict__ keys, const uint32_t* __restrict__ M,
    uint32_t* __restrict__ bs, uint32_t* __restrict__ bt, int N)
{
    __shared__ uint32_t ls[4], lt[4];
    uint32_t tau = M[2];
    int base_i = blockIdx.x * 1024 + threadIdx.x * 4;
    uint32_t cs = 0, ct = 0;
    for (int j = 0; j < 4; j++) {
        int i = base_i + j;
        if (i < N) {
            uint32_t kk = keys[i];
            cs += (kk > tau);
            ct += (kk == tau);
        }
    }
    for (int off = 32; off; off >>= 1) {
        cs += __shfl_xor(cs, off);
        ct += __shfl_xor(ct, off);
    }
    int lane = threadIdx.x & 63, wv = threadIdx.x >> 6;
    if (lane == 0) { ls[wv] = cs; lt[wv] = ct; }
    __syncthreads();
    if (threadIdx.x == 0) {
        uint32_t a = 0, b = 0;
        for (int wq = 0; wq < 4; wq++) { a += ls[wq]; b += lt[wq]; }
        bs[blockIdx.x] = a; bt[blockIdx.x] = b;
    }
}

__global__ __launch_bounds__(128) void scanblocks(
    uint32_t* M, const uint32_t* __restrict__ bsv, const uint32_t* __restrict__ btv,
    uint32_t* __restrict__ ssv, uint32_t* __restrict__ stv, int nb, uint32_t k)
{
    __shared__ uint32_t A[128], B[128];
    int t = threadIdx.x;
    if (nb <= 128) {
        uint32_t a = (t < nb) ? bsv[t] : 0u;
        uint32_t b = (t < nb) ? btv[t] : 0u;
        A[t] = a; B[t] = b;
        __syncthreads();
        for (int off = 1; off < 128; off <<= 1) {
            uint32_t ua = (t >= off) ? A[t - off] : 0u;
            uint32_t ub = (t >= off) ? B[t - off] : 0u;
            __syncthreads();
            A[t] += ua; B[t] += ub;
            __syncthreads();
        }
        if (t < nb) { ssv[t] = A[t] - a; stv[t] = B[t] - b; }
        if (t == 127) M[3] = k - A[127];
    } else if (t == 0) {
        uint32_t a = 0, b = 0;
        for (int i = 0; i < nb; i++) {
            ssv[i] = a; stv[i] = b;
            a += bsv[i]; b += btv[i];
        }
        M[3] = k - a;
    }
}

__global__ __launch_bounds__(256) void select_write(
    const uint32_t* __restrict__ keys, const uint32_t* __restrict__ M,
    const uint32_t* __restrict__ ss, const uint32_t* __restrict__ st,
    uint32_t* __restrict__ sel, int N)
{
    uint32_t tau = M[2], need = M[3];
    int t = threadIdx.x, lane = t & 63, wv = t >> 6;
    int base_i = blockIdx.x * 1024 + t * 4;
    uint32_t fs[4], ft[4];
    uint32_t cs = 0, ct = 0;
    for (int j = 0; j < 4; j++) {
        int i = base_i + j;
        uint32_t kk = (i < N) ? keys[i] : 0u;
        fs[j] = (i < N) && (kk > tau);
        ft[j] = (i < N) && (kk == tau);
        cs += fs[j]; ct += ft[j];
    }
    uint32_t is_ = cs, it_ = ct;
    for (int off = 1; off < 64; off <<= 1) {
        uint32_t vs = __shfl_up(is_, off);
        uint32_t vt = __shfl_up(it_, off);
        if (lane >= off) { is_ += vs; it_ += vt; }
    }
    uint32_t wes = is_ - cs, wet = it_ - ct;
    __shared__ uint32_t lws[4], lwt[4];
    if (lane == 63) { lws[wv] = is_; lwt[wv] = it_; }
    __syncthreads();
    uint32_t wos = 0, wot = 0;
    for (int wq = 0; wq < wv; wq++) { wos += lws[wq]; wot += lwt[wq]; }
    uint32_t gs = ss[blockIdx.x] + wos + wes;
    uint32_t gt = st[blockIdx.x] + wot + wet;
    for (int j = 0; j < 4; j++) {
        int i = base_i + j;
        if (fs[j]) {
            uint32_t pos = gs + (gt < need ? gt : need);
            sel[pos] = (uint32_t)i;
        } else if (ft[j]) {
            if (gt < need) sel[gs + gt] = (uint32_t)i;
        }
        gs += fs[j]; gt += ft[j];
    }
}

// ---------------- Kernel E: write hidden rows ----------------
__global__ __launch_bounds__(256) void write_hidden(
    const float* __restrict__ x, const uint32_t* __restrict__ sel,
    const float* __restrict__ attn, const float* __restrict__ coef,
    float* __restrict__ out, int K)
{
    int wv = threadIdx.x >> 6, lane = threadIdx.x & 63;
    int p = blockIdx.x * 4 + wv;
    if (p >= K) return;
    uint32_t i = sel[p];
    float s = attn[i] * coef[i];
    const float4* xr = (const float4*)(x + (size_t)i * 512);
    float4* orow = (float4*)(out + (size_t)p * 512);
#pragma unroll
    for (int it = 0; it < 2; it++) {
        float4 v = xr[lane + it * 64];
        float4 o;
        o.x = v.x * s; o.y = v.y * s; o.z = v.z * s; o.w = v.w * s;
        orow[lane + it * 64] = o;
    }
}

extern "C" void kernel_launch(void* const* d_in, const int* in_sizes, int n_in,
                              void* d_out, int out_size, void* d_ws, size_t ws_size,
                              hipStream_t stream)
{
    const float* x    = (const float*)d_in[0];
    const float* adj  = (const float*)d_in[1];
    const float* w    = (const float*)d_in[2];
    const float* bias = (const float*)d_in[3];
    const float* w1p  = (const float*)d_in[4];
    const float* bp   = (const float*)d_in[5];
    const int* erow = (const int*)d_in[6];
    const int* ecol = (const int*)d_in[7];

    int D = in_sizes[2];          // 512
    int N = in_sizes[0] / D;      // 100000
    int E = in_sizes[1];          // 3200000
    int K = N / 2;                // keep_ratio 0.5

    char* ws = (char*)d_ws;
    float*   support = (float*)(ws);                                  // N*4 @ 0
    float*   coef    = (float*)(ws + (512 << 10));                    // N*4 @ 0.5M
    double*  base    = (double*)(ws + (1 << 20));                     // N*8 @ 1M
    float*   attn    = (float*)(ws + (2 << 20));                      // N*4 @ 2M
    uint32_t* keys   = (uint32_t*)(ws + (2 << 20) + (512 << 10));     // N*4 @ 2.5M
    unsigned long long* agg = (unsigned long long*)(ws + (3 << 20));  // N*8 @ 3M
    uint32_t* hist1  = (uint32_t*)(ws + (4 << 20));                   // 256K @ 4M
    uint32_t* hist2  = (uint32_t*)(ws + (4 << 20) + (256 << 10));     // 256K @ 4.25M
    uint32_t* M      = (uint32_t*)(ws + 4718592);                     // @ 4.5M
    uint32_t* bsv = M + 8;
    uint32_t* btv = M + 8 + 128;
    uint32_t* ssv = M + 8 + 256;
    uint32_t* stv = M + 8 + 384;
    uint32_t* sel  = (uint32_t*)(ws + 4849664);                       // K*4 @ 4.625M
    uint32_t* tot  = (uint32_t*)(ws + 5242880);                       // 4K @ 5M
    uint32_t* bas  = (uint32_t*)(ws + 5242880 + 4096);                // 12K @ 5M+4K
    uint32_t* P    = (uint32_t*)(ws + 5242880 + 16384);               // nbuk*nchunks*4 @ 5M+16K
    int*      prod = (int*)(ws + (9 << 20));                          // E*4 @ 9M
    uint8_t*  rowlo= (uint8_t*)(ws + (22 << 20));                     // E @ 22M

    float* hidden_out = (float*)d_out;
    float* attn_out   = (float*)d_out + (size_t)K * D;

    int nbuk = (N + BROWS - 1) / BROWS;        // 391
    int nchunks = (E + CHUNK - 1) / CHUNK;     // 1042
    bool fast = (ws_size >= (size_t)(26 << 20)) && (nbuk <= 512) &&
                ((size_t)nbuk * nchunks * 4 <= (size_t)(3 << 20) + (1008 << 10));

    hipMemsetAsync(ws + (4 << 20), 0, (512 << 10) + 4096, stream); // hist1,hist2,M

    rowstats<<<(N + 3) / 4, 256, 0, stream>>>(x, w, bias, w1p, bp, support, coef, base, N);

    if (fast) {
        edge_hist<<<nchunks, 256, 0, stream>>>(erow, P, E, nbuk, nchunks);
        scan_parts<<<nbuk, 64, 0, stream>>>(P, tot, nchunks);
        scan_base<<<1, 1024, 0, stream>>>(tot, bas, nbuk);
        edge_sort_scatter<<<nchunks, 256, 0, stream>>>(erow, ecol, adj, support, P, bas,
                                                       prod, rowlo, E, nbuk, nchunks);
        bucket_reduce<<<nbuk, 256, 0, stream>>>(prod, rowlo, bas, agg, N);
    } else {
        hipMemsetAsync(agg, 0, (size_t)N * 8, stream);
        spmv<<<(E + 255) / 256, 256, 0, stream>>>(erow, ecol, adj, support, agg, E);
    }

    attn_kernel<<<(N + 255) / 256, 256, 0, stream>>>(agg, base, w1p, attn, keys, hist1, attn_out, N);
    select_bucket<<<1, 1024, 0, stream>>>(hist1, M, 0, (uint32_t)K);
    hist_low<<<(N + 255) / 256, 256, 0, stream>>>(keys, M, hist2, N);
    select_bucket<<<1, 1024, 0, stream>>>(hist2, M, 1, (uint32_t)K);
    int nb = (N + 1023) / 1024;
    blocksum<<<nb, 256, 0, stream>>>(keys, M, bsv, btv, N);
    scanblocks<<<1, 128, 0, stream>>>(M, bsv, btv, ssv, stv, nb, (uint32_t)K);
    select_write<<<nb, 256, 0, stream>>>(keys, M, ssv, stv, sel, N);
    write_hidden<<<(K + 3) / 4, 256, 0, stream>>>(x, sel, attn, coef, hidden_out, K);
}

// Round 5
// 378.779 us; speedup vs baseline: 1.3094x; 1.0820x over previous
//
#include <hip/hip_runtime.h>
#include <stdint.h>

#define CHUNK 3072
#define BROWS 256   // rows per bucket (q = row >> 8)

// ---------------- zero scratch (replaces pathological runtime fill blit) ----
__global__ __launch_bounds__(256) void zero_ws(
    uint32_t* __restrict__ hist1, uint32_t* __restrict__ hist2,
    uint32_t* __restrict__ M)
{
    int i = blockIdx.x * 256 + threadIdx.x;
    hist1[i] = 0u;
    hist2[i] = 0u;
    if (i < 8) M[i] = 0u;
}

// ---------------- Kernel A: per-row stats ----------------
__global__ __launch_bounds__(256) void rowstats(
    const float* __restrict__ x, const float* __restrict__ w,
    const float* __restrict__ bias, const float* __restrict__ w1p,
    const float* __restrict__ bp,
    float* __restrict__ support, float* __restrict__ coef,
    double* __restrict__ base, int N)
{
    int wv = threadIdx.x >> 6, lane = threadIdx.x & 63;
    int row = blockIdx.x * 4 + wv;
    if (row >= N) return;
    const float4* xr = (const float4*)(x + (size_t)row * 512);
    const float4* wr = (const float4*)(w);
    float dot = 0.f, ss = 0.f;
#pragma unroll
    for (int it = 0; it < 2; it++) {
        float4 xv = xr[lane + it * 64];
        float4 wv4 = wr[lane + it * 64];
        dot += xv.x * wv4.x + xv.y * wv4.y + xv.z * wv4.z + xv.w * wv4.w;
        ss  += xv.x * xv.x + xv.y * xv.y + xv.z * xv.z + xv.w * xv.w;
    }
    for (int off = 32; off; off >>= 1) {
        dot += __shfl_xor(dot, off);
        ss  += __shfl_xor(ss, off);
    }
    if (lane == 0) {
        double n = sqrt((double)ss); if (n < 1e-15) n = 1e-15;
        double t = n; const double lim = 1.0 - 1e-7; if (t > lim) t = lim;
        double cf = atanh(t) / n;
        double s = cf * (double)dot;
        const double maxn = 0.996;
        double b0 = (double)bias[0];
        double r;
        if (b0 == 0.0) {
            // expmap0(0)=0 exactly (np MIN_NORM path), mobius_add(s,0)=s exactly
            r = s;
        } else {
            double nb = fabs(b0); if (nb < 1e-15) nb = 1e-15;
            double hb = tanh(nb) * b0 / nb;
            double nh = fabs(hb); if (nh < 1e-15) nh = 1e-15;
            if (nh > maxn) hb = hb / nh * maxn;
            double x2 = s * s, y2 = hb * hb, xy = s * hb;
            double num = (1.0 + 2.0 * xy + y2) * s + (1.0 - x2) * hb;
            double den = 1.0 + 2.0 * xy + x2 * y2;
            if (den < 1e-15) den = 1e-15;
            r = num / den;
        }
        double nr = fabs(r); if (nr < 1e-15) nr = 1e-15;
        if (nr > maxn) r = r / nr * maxn;
        support[row] = (float)r;
        coef[row] = (float)cf;
        double w1 = (double)w1p[0];
        double bb = (double)bp[0];
        base[row] = (1.0 - w1) * (1.0 - n) + bb;
    }
}

// ---------------- fallback SpMV (atomic) ----------------
__global__ __launch_bounds__(256) void spmv(
    const int* __restrict__ rows, const int* __restrict__ cols,
    const float* __restrict__ adj, const float* __restrict__ support,
    unsigned long long* __restrict__ agg, int E)
{
    int e = blockIdx.x * 256 + threadIdx.x;
    if (e >= E) return;
    double p = (double)adj[e] * (double)support[cols[e]];
    long long f = llrint(p * 1073741824.0); // 2^30
    atomicAdd(&agg[rows[e]], (unsigned long long)f);
}

// ---------------- phase 1: per-chunk histogram ----------------
__global__ __launch_bounds__(256) void edge_hist(
    const int* __restrict__ rows, uint32_t* __restrict__ P,
    int E, int nbuk, int nchunks)
{
    __shared__ uint32_t h[512];
    int b = blockIdx.x;
    for (int q = threadIdx.x; q < 512; q += 256) h[q] = 0u;
    __syncthreads();
    int s = b * CHUNK, e_end = min(E, s + CHUNK);
    for (int i = s + threadIdx.x; i < e_end; i += 256)
        atomicAdd(&h[((uint32_t)rows[i]) >> 8], 1u);
    __syncthreads();
    for (int q = threadIdx.x; q < nbuk; q += 256)
        P[(size_t)q * nchunks + b] = h[q];
}

// phase 2a: per-bucket exclusive scan over chunks (one wave per bucket)
__global__ __launch_bounds__(64) void scan_parts(
    uint32_t* __restrict__ P, uint32_t* __restrict__ tot, int nchunks)
{
    int q = blockIdx.x, lane = threadIdx.x;
    uint32_t* row = P + (size_t)q * nchunks;
    uint32_t run = 0;
    for (int base = 0; base < nchunks; base += 64) {
        int idx = base + lane;
        uint32_t v = (idx < nchunks) ? row[idx] : 0u;
        uint32_t inc = v;
        for (int off = 1; off < 64; off <<= 1) {
            uint32_t t = __shfl_up(inc, off);
            if (lane >= off) inc += t;
        }
        if (idx < nchunks) row[idx] = run + inc - v;
        run += __shfl(inc, 63);
    }
    if (lane == 0) tot[q] = run;
}

// phase 2b: exclusive scan of bucket totals -> bas[nbuk+1]
__global__ __launch_bounds__(1024) void scan_base(
    const uint32_t* __restrict__ tot, uint32_t* __restrict__ bas, int nbuk)
{
    __shared__ uint32_t lds[1024];
    int t = threadIdx.x;
    uint32_t v = (t < nbuk) ? tot[t] : 0u;
    lds[t] = v;
    __syncthreads();
    for (int off = 1; off < 1024; off <<= 1) {
        uint32_t u = (t >= off) ? lds[t - off] : 0u;
        __syncthreads();
        lds[t] += u;
        __syncthreads();
    }
    if (t == 0) bas[0] = 0u;
    if (t < nbuk) bas[t + 1] = lds[t];
}

// phase 3: block-local counting sort in LDS, then coalesced dump
__global__ __launch_bounds__(256) void edge_sort_scatter(
    const int* __restrict__ rows, const int* __restrict__ cols,
    const float* __restrict__ adj, const float* __restrict__ support,
    const uint32_t* __restrict__ P, const uint32_t* __restrict__ bas,
    int* __restrict__ prod, uint8_t* __restrict__ rowlo,
    int E, int nbuk, int nchunks)
{
    __shared__ uint32_t lcnt[512], lofs[512], gbase[512], sc[512];
    __shared__ int      lpi[CHUNK];
    __shared__ uint16_t lq[CHUNK];
    __shared__ uint8_t  lrl[CHUNK];
    int b = blockIdx.x, t = threadIdx.x;
    int s = b * CHUNK;
    int n = min(CHUNK, E - s);
    if (n <= 0) return;
    for (int q = t; q < 512; q += 256) lcnt[q] = 0u;
    __syncthreads();
    for (int i = t; i < n; i += 256)
        atomicAdd(&lcnt[((uint32_t)rows[s + i]) >> 8], 1u);
    __syncthreads();
    uint32_t a0 = lcnt[t], a1 = lcnt[t + 256];
    sc[t] = a0; sc[t + 256] = a1;
    __syncthreads();
    for (int off = 1; off < 512; off <<= 1) {
        uint32_t u0 = (t >= off) ? sc[t - off] : 0u;
        uint32_t u1 = ((t + 256) >= off) ? sc[t + 256 - off] : 0u;
        __syncthreads();
        sc[t] += u0; sc[t + 256] += u1;
        __syncthreads();
    }
    lofs[t] = sc[t] - a0;
    lofs[t + 256] = sc[t + 256] - a1;
    for (int q = t; q < 512; q += 256) {
        gbase[q] = (q < nbuk) ? (bas[q] + P[(size_t)q * nchunks + b]) : 0u;
        lcnt[q] = 0u;
    }
    __syncthreads();
    for (int i = t; i < n; i += 256) {
        uint32_t r = (uint32_t)rows[s + i];
        uint32_t q = r >> 8;
        double p = (double)adj[s + i] * (double)support[cols[s + i]];
        int pi = (int)llrint(p * 1073741824.0); // 2^30
        uint32_t rank = atomicAdd(&lcnt[q], 1u);
        uint32_t slot = lofs[q] + rank;
        lpi[slot] = pi;
        lq[slot]  = (uint16_t)q;
        lrl[slot] = (uint8_t)(r & 255u);
    }
    __syncthreads();
    for (int i = t; i < n; i += 256) {
        uint32_t q = lq[i];
        uint32_t gpos = gbase[q] + ((uint32_t)i - lofs[q]);
        prod[gpos]  = lpi[i];
        rowlo[gpos] = lrl[i];
    }
}

// phase 4: per-bucket deterministic integer reduction -> agg
__global__ __launch_bounds__(256) void bucket_reduce(
    const int* __restrict__ prod, const uint8_t* __restrict__ rowlo,
    const uint32_t* __restrict__ bas, unsigned long long* __restrict__ agg, int N)
{
    __shared__ unsigned long long acc[BROWS];
    int q = blockIdx.x;
    acc[threadIdx.x] = 0ull;
    __syncthreads();
    uint32_t s = bas[q], e = bas[q + 1];
    for (uint32_t i = s + threadIdx.x; i < e; i += 256)
        atomicAdd(&acc[rowlo[i]], (unsigned long long)(long long)prod[i]);
    __syncthreads();
    int gr = q * BROWS + threadIdx.x;
    if (gr < N) agg[gr] = acc[threadIdx.x];
}

// ---------------- Kernel C: attn + keys + coarse histogram ----------------
__global__ __launch_bounds__(256) void attn_kernel(
    const unsigned long long* __restrict__ agg, const double* __restrict__ base,
    const float* __restrict__ w1p,
    float* __restrict__ attn, uint32_t* __restrict__ keys,
    uint32_t* __restrict__ hist1, float* __restrict__ attn_out, int N)
{
    int i = blockIdx.x * 256 + threadIdx.x;
    if (i >= N) return;
    double a = (double)(long long)agg[i] * (1.0 / 1073741824.0);
    double na = fabs(a); if (na < 1e-15) na = 1e-15;
    double sc_ = tanh(na) * a / na;
    const double maxn = 0.996;
    double ns = fabs(sc_); if (ns < 1e-15) ns = 1e-15;
    if (ns > maxn) sc_ = sc_ / ns * maxn;
    double w1 = (double)w1p[0];
    double at = w1 * tanh(sc_) + base[i];
    float af = (float)at;
    attn[i] = af;
    attn_out[i] = af;
    union { float f; uint32_t u; } cv; cv.f = af;
    uint32_t key = cv.u ^ ((cv.u >> 31) ? 0xFFFFFFFFu : 0x80000000u);
    keys[i] = key;
    atomicAdd(&hist1[key >> 16], 1u);
}

// ---------------- find bucket containing k-th largest ----------------
__global__ __launch_bounds__(1024) void select_bucket(
    const uint32_t* __restrict__ hist, uint32_t* M, int mode, uint32_t k)
{
    __shared__ uint32_t lds[1024];
    int t = threadIdx.x;
    uint32_t ktarget = (mode == 0) ? k : (k - M[1]);
    uint32_t csum = 0;
    for (int j = 0; j < 64; j++) csum += hist[t * 64 + j];
    lds[t] = csum;
    __syncthreads();
    for (int off = 1; off < 1024; off <<= 1) {
        uint32_t v = (t + off < 1024) ? lds[t + off] : 0u;
        __syncthreads();
        lds[t] += v;
        __syncthreads();
    }
    uint32_t run = (t + 1 < 1024) ? lds[t + 1] : 0u;
    for (int j = 63; j >= 0; j--) {
        uint32_t c = hist[t * 64 + j];
        uint32_t nr = run + c;
        if (nr >= ktarget && run < ktarget) {
            if (mode == 0) { M[0] = (uint32_t)(t * 64 + j); M[1] = run; }
            else           { M[2] = (M[0] << 16) | (uint32_t)(t * 64 + j); }
        }
        run = nr;
    }
}

__global__ __launch_bounds__(256) void hist_low(
    const uint32_t* __restrict__ keys, const uint32_t* __restrict__ M,
    uint32_t* __restrict__ hist2, int N)
{
    int i = blockIdx.x * 256 + threadIdx.x;
    if (i >= N) return;
    uint32_t key = keys[i];
    if ((key >> 16) == M[0]) atomicAdd(&hist2[key & 0xFFFFu], 1u);
}

// ---------------- selection prefix machinery ----------------
__global__ __launch_bounds__(256) void blocksum(
    const uint32_t* __restrict__ keys, const uint32_t* __restrict__ M,
    uint32_t* __restrict__ bs, uint32_t* __restrict__ bt, int N)
{
    __shared__ uint32_t ls[4], lt[4];
    uint32_t tau = M[2];
    int base_i = blockIdx.x * 1024 + threadIdx.x * 4;
    uint32_t cs = 0, ct = 0;
    for (int j = 0; j < 4; j++) {
        int i = base_i + j;
        if (i < N) {
            uint32_t kk = keys[i];
            cs += (kk > tau);
            ct += (kk == tau);
        }
    }
    for (int off = 32; off; off >>= 1) {
        cs += __shfl_xor(cs, off);
        ct += __shfl_xor(ct, off);
    }
    int lane = threadIdx.x & 63, wv = threadIdx.x >> 6;
    if (lane == 0) { ls[wv] = cs; lt[wv] = ct; }
    __syncthreads();
    if (threadIdx.x == 0) {
        uint32_t a = 0, b = 0;
        for (int wq = 0; wq < 4; wq++) { a += ls[wq]; b += lt[wq]; }
        bs[blockIdx.x] = a; bt[blockIdx.x] = b;
    }
}

__global__ __launch_bounds__(128) void scanblocks(
    uint32_t* M, const uint32_t* __restrict__ bsv, const uint32_t* __restrict__ btv,
    uint32_t* __restrict__ ssv, uint32_t* __restrict__ stv, int nb, uint32_t k)
{
    __shared__ uint32_t A[128], B[128];
    int t = threadIdx.x;
    if (nb <= 128) {
        uint32_t a = (t < nb) ? bsv[t] : 0u;
        uint32_t b = (t < nb) ? btv[t] : 0u;
        A[t] = a; B[t] = b;
        __syncthreads();
        for (int off = 1; off < 128; off <<= 1) {
            uint32_t ua = (t >= off) ? A[t - off] : 0u;
            uint32_t ub = (t >= off) ? B[t - off] : 0u;
            __syncthreads();
            A[t] += ua; B[t] += ub;
            __syncthreads();
        }
        if (t < nb) { ssv[t] = A[t] - a; stv[t] = B[t] - b; }
        if (t == 127) M[3] = k - A[127];
    } else if (t == 0) {
        uint32_t a = 0, b = 0;
        for (int i = 0; i < nb; i++) {
            ssv[i] = a; stv[i] = b;
            a += bsv[i]; b += btv[i];
        }
        M[3] = k - a;
    }
}

__global__ __launch_bounds__(256) void select_write(
    const uint32_t* __restrict__ keys, const uint32_t* __restrict__ M,
    const uint32_t* __restrict__ ss, const uint32_t* __restrict__ st,
    uint32_t* __restrict__ sel, int N)
{
    uint32_t tau = M[2], need = M[3];
    int t = threadIdx.x, lane = t & 63, wv = t >> 6;
    int base_i = blockIdx.x * 1024 + t * 4;
    uint32_t fs[4], ft[4];
    uint32_t cs = 0, ct = 0;
    for (int j = 0; j < 4; j++) {
        int i = base_i + j;
        uint32_t kk = (i < N) ? keys[i] : 0u;
        fs[j] = (i < N) && (kk > tau);
        ft[j] = (i < N) && (kk == tau);
        cs += fs[j]; ct += ft[j];
    }
    uint32_t is_ = cs, it_ = ct;
    for (int off = 1; off < 64; off <<= 1) {
        uint32_t vs = __shfl_up(is_, off);
        uint32_t vt = __shfl_up(it_, off);
        if (lane >= off) { is_ += vs; it_ += vt; }
    }
    uint32_t wes = is_ - cs, wet = it_ - ct;
    __shared__ uint32_t lws[4], lwt[4];
    if (lane == 63) { lws[wv] = is_; lwt[wv] = it_; }
    __syncthreads();
    uint32_t wos = 0, wot = 0;
    for (int wq = 0; wq < wv; wq++) { wos += lws[wq]; wot += lwt[wq]; }
    uint32_t gs = ss[blockIdx.x] + wos + wes;
    uint32_t gt = st[blockIdx.x] + wot + wet;
    for (int j = 0; j < 4; j++) {
        int i = base_i + j;
        if (fs[j]) {
            uint32_t pos = gs + (gt < need ? gt : need);
            sel[pos] = (uint32_t)i;
        } else if (ft[j]) {
            if (gt < need) sel[gs + gt] = (uint32_t)i;
        }
        gs += fs[j]; gt += ft[j];
    }
}

// ---------------- Kernel E: write hidden rows ----------------
__global__ __launch_bounds__(256) void write_hidden(
    const float* __restrict__ x, const uint32_t* __restrict__ sel,
    const float* __restrict__ attn, const float* __restrict__ coef,
    float* __restrict__ out, int K)
{
    int wv = threadIdx.x >> 6, lane = threadIdx.x & 63;
    int p = blockIdx.x * 4 + wv;
    if (p >= K) return;
    uint32_t i = sel[p];
    float s = attn[i] * coef[i];
    const float4* xr = (const float4*)(x + (size_t)i * 512);
    float4* orow = (float4*)(out + (size_t)p * 512);
#pragma unroll
    for (int it = 0; it < 2; it++) {
        float4 v = xr[lane + it * 64];
        float4 o;
        o.x = v.x * s; o.y = v.y * s; o.z = v.z * s; o.w = v.w * s;
        orow[lane + it * 64] = o;
    }
}

extern "C" void kernel_launch(void* const* d_in, const int* in_sizes, int n_in,
                              void* d_out, int out_size, void* d_ws, size_t ws_size,
                              hipStream_t stream)
{
    const float* x    = (const float*)d_in[0];
    const float* adj  = (const float*)d_in[1];
    const float* w    = (const float*)d_in[2];
    const float* bias = (const float*)d_in[3];
    const float* w1p  = (const float*)d_in[4];
    const float* bp   = (const float*)d_in[5];
    const int* erow = (const int*)d_in[6];
    const int* ecol = (const int*)d_in[7];

    int D = in_sizes[2];          // 512
    int N = in_sizes[0] / D;      // 100000
    int E = in_sizes[1];          // 3200000
    int K = N / 2;                // keep_ratio 0.5

    char* ws = (char*)d_ws;
    float*   support = (float*)(ws);                                  // N*4 @ 0
    float*   coef    = (float*)(ws + (512 << 10));                    // N*4 @ 0.5M
    double*  base    = (double*)(ws + (1 << 20));                     // N*8 @ 1M
    float*   attn    = (float*)(ws + (2 << 20));                      // N*4 @ 2M
    uint32_t* keys   = (uint32_t*)(ws + (2 << 20) + (512 << 10));     // N*4 @ 2.5M
    unsigned long long* agg = (unsigned long long*)(ws + (3 << 20));  // N*8 @ 3M
    uint32_t* hist1  = (uint32_t*)(ws + (4 << 20));                   // 256K @ 4M
    uint32_t* hist2  = (uint32_t*)(ws + (4 << 20) + (256 << 10));     // 256K @ 4.25M
    uint32_t* M      = (uint32_t*)(ws + 4718592);                     // @ 4.5M
    uint32_t* bsv = M + 8;
    uint32_t* btv = M + 8 + 128;
    uint32_t* ssv = M + 8 + 256;
    uint32_t* stv = M + 8 + 384;
    uint32_t* sel  = (uint32_t*)(ws + 4849664);                       // K*4 @ 4.625M
    uint32_t* tot  = (uint32_t*)(ws + 5242880);                       // 4K @ 5M
    uint32_t* bas  = (uint32_t*)(ws + 5242880 + 4096);                // 12K @ 5M+4K
    uint32_t* P    = (uint32_t*)(ws + 5242880 + 16384);               // nbuk*nchunks*4 @ 5M+16K
    int*      prod = (int*)(ws + (9 << 20));                          // E*4 @ 9M
    uint8_t*  rowlo= (uint8_t*)(ws + (22 << 20));                     // E @ 22M

    float* hidden_out = (float*)d_out;
    float* attn_out   = (float*)d_out + (size_t)K * D;

    int nbuk = (N + BROWS - 1) / BROWS;        // 391
    int nchunks = (E + CHUNK - 1) / CHUNK;     // 1042
    bool fast = (ws_size >= (size_t)(26 << 20)) && (nbuk <= 512) &&
                ((size_t)nbuk * nchunks * 4 <= (size_t)(3 << 20) + (1008 << 10));

    zero_ws<<<65536 / 256, 256, 0, stream>>>(hist1, hist2, M);

    rowstats<<<(N + 3) / 4, 256, 0, stream>>>(x, w, bias, w1p, bp, support, coef, base, N);

    if (fast) {
        edge_hist<<<nchunks, 256, 0, stream>>>(erow, P, E, nbuk, nchunks);
        scan_parts<<<nbuk, 64, 0, stream>>>(P, tot, nchunks);
        scan_base<<<1, 1024, 0, stream>>>(tot, bas, nbuk);
        edge_sort_scatter<<<nchunks, 256, 0, stream>>>(erow, ecol, adj, support, P, bas,
                                                       prod, rowlo, E, nbuk, nchunks);
        bucket_reduce<<<nbuk, 256, 0, stream>>>(prod, rowlo, bas, agg, N);
    } else {
        hipMemsetAsync(agg, 0, (size_t)N * 8, stream);
        spmv<<<(E + 255) / 256, 256, 0, stream>>>(erow, ecol, adj, support, agg, E);
    }

    attn_kernel<<<(N + 255) / 256, 256, 0, stream>>>(agg, base, w1p, attn, keys, hist1, attn_out, N);
    select_bucket<<<1, 1024, 0, stream>>>(hist1, M, 0, (uint32_t)K);
    hist_low<<<(N + 255) / 256, 256, 0, stream>>>(keys, M, hist2, N);
    select_bucket<<<1, 1024, 0, stream>>>(hist2, M, 1, (uint32_t)K);
    int nb = (N + 1023) / 1024;
    blocksum<<<nb, 256, 0, stream>>>(keys, M, bsv, btv, N);
    scanblocks<<<1, 128, 0, stream>>>(M, bsv, btv, ssv, stv, nb, (uint32_t)K);
    select_write<<<nb, 256, 0, stream>>>(keys, M, ssv, stv, sel, N);
    write_hidden<<<(K + 3) / 4, 256, 0, stream>>>(x, sel, attn, coef, hidden_out, K);
}